// Round 3
// baseline (427.943 us; speedup 1.0000x reference)
//
#include <hip/hip_runtime.h>

// Swin window attention, MFMA bf16 path. fp32 global in/out.
// R8: clean 3-blocks/CU test. LDS 54,016B: x gets its own region (P overlays
// it in Phase C only), Q/O share, K separate, V in dense B-frags. All
// row-major tiles stride-128 + XOR swizzle (col ^= (row&7)<<3) => conflict-
// free b128 frag reads AND the size cut that fits 3 blocks. Phase B streams
// A-frags from LDS (no big register arrays -> no spills at the 85-VGPR cap).
// launch_bounds(512,6). Barriers: 3.

#define NTOK  49
#define DIMC  128
#define NBLK  4096
#define SCALE 0.17677669529663687f   // 32^-0.5
#define LOG2E 1.4426950408889634f
#define NMASK -144.26950408889634f   // -100 * LOG2E

typedef __attribute__((ext_vector_type(8))) short bf16x8;
typedef __attribute__((ext_vector_type(4))) float f32x4;

// ---- workspace layout (ushort units) ----
#define WS_QKVW 0        // 384*128 bf16 (q rows pre-scaled by SCALE*LOG2E)
#define WS_PROJW 49152   // 128*128 bf16
#define WS_BIAS  65536   // [h][mt][nt][lane][reg] 4*4*4*64*4 bf16 (x LOG2E)

// ---- LDS layout (ushort units) ----
// XP: [49][128] swz: x stage (Phase A/B) -> P [2 g][49][64 keys] (Phase C).
// Q : [49][128] swz: Q (col=h*32+d); attn-out O overlays same cols in C.
// K : [49][128] swz.
// VB: V as B-frags [4 h][2 ks2][2 nt2][64 lane][8] (linear, conflict-free).
#define XP_OFF 0
#define Q_OFF  6272
#define K_OFF  12544
#define VB_OFF 18816
#define SMEM_TOT 27008   // 54,016 B -> 3 blocks/CU @ 512 thr = 24 waves/CU

// XOR swizzle: row-major [49][128] shorts, granule 8 shorts (16B).
// Bijective per row; b128 reads stay aligned; banks tile exactly.
#define SWZ(r, c) ((r) * 128 + ((c) ^ (((r) & 7) << 3)))

__device__ __forceinline__ unsigned int pkbf2(float f0, float f1) {
    union { float f; unsigned int i; } a, b; a.f = f0; b.f = f1;
    return __builtin_amdgcn_perm(b.i + 0x8000u, a.i + 0x8000u, 0x07060302u);
}
__device__ __forceinline__ unsigned short f2b_r(float f) {
    union { float f; unsigned int i; } v; v.f = f;
    return (unsigned short)((v.i + 0x8000u) >> 16);
}
__device__ __forceinline__ float b2f_lo(unsigned int u) {
    union { unsigned int i; float f; } v; v.i = u << 16; return v.f;
}
__device__ __forceinline__ float b2f_hi(unsigned int u) {
    union { unsigned int i; float f; } v; v.i = u & 0xFFFF0000u; return v.f;
}
__device__ __forceinline__ float exp2_hw(float x) {
    float r; asm("v_exp_f32 %0, %1" : "=v"(r) : "v"(x)); return r;
}

// Swin shift-mask group id. GRID=56, WS=7, shift=3: segments [0,49)/[49,53)/[53,56)
__device__ __forceinline__ int seg3(int c) { return (c < 49) ? 0 : ((c < 53) ? 1 : 2); }

// ---------------- prep: weights fp32->bf16 (+SCALE*LOG2E fold), bias -> frag order
__global__ __launch_bounds__(256)
void prep(const float* __restrict__ qkv_w, const float* __restrict__ proj_w,
          const float* __restrict__ bias_t, const int* __restrict__ rel_idx,
          unsigned short* __restrict__ ws)
{
    int idx = blockIdx.x * 256 + threadIdx.x;
    if (idx < 8192) {
        int base = idx * 8;
        const float* sp = (base < 49152) ? (qkv_w + base) : (proj_w + (base - 49152));
        float sc = (base < 16384) ? (SCALE * LOG2E) : 1.0f;  // q rows pre-scaled
        float4 a = *(const float4*)sp;
        float4 b = *(const float4*)(sp + 4);
        uint4 u;
        u.x = pkbf2(a.x * sc, a.y * sc);
        u.y = pkbf2(a.z * sc, a.w * sc);
        u.z = pkbf2(b.x * sc, b.y * sc);
        u.w = pkbf2(b.z * sc, b.w * sc);
        *(uint4*)(ws + base) = u;
    } else {
        int i = idx - 8192;                         // [0, 16384)
        int reg = i & 3, lane = (i >> 2) & 63, nt = (i >> 8) & 3,
            mt = (i >> 10) & 3, h = (i >> 12) & 3;
        int row = mt * 16 + (lane >> 4) * 4 + reg;
        int col = nt * 16 + (lane & 15);
        float v = 0.f;
        if (row < NTOK && col < NTOK)
            v = bias_t[rel_idx[row * NTOK + col] * 4 + h] * LOG2E;
        ws[WS_BIAS + i] = f2b_r(v);
    }
}

// ---------------- main: 512 threads = 8 waves, one window ----------------
__global__ __launch_bounds__(512, 6)
void win_attn(const float* __restrict__ x,
              const float* __restrict__ qkv_b,
              const float* __restrict__ proj_b,
              const unsigned short* __restrict__ ws,
              float* __restrict__ out)
{
    __shared__ unsigned short smem[SMEM_TOT];
    const int b    = blockIdx.x;
    const int w    = b & 63;
    const int tid  = threadIdx.x;
    const int wv   = tid >> 6;     // wave id 0..7
    const int lane = tid & 63;
    const int qg   = lane >> 4;    // quad
    const int l15  = lane & 15;

    // ---- Phase A: stage x -> bf16 LDS [49][128] swz in XP ----
    {
        const float4* xg = (const float4*)(x + (size_t)b * (NTOK * DIMC));
        #pragma unroll
        for (int it = 0; it < 4; it++) {
            int i = tid + it * 512;
            if (i < NTOK * DIMC / 4) {
                float4 v = xg[i];
                int row = i >> 5, col = (i & 31) * 4;
                uint2 u; u.x = pkbf2(v.x, v.y); u.y = pkbf2(v.z, v.w);
                *(uint2*)(smem + XP_OFF + SWZ(row, col)) = u;
            }
        }
    }
    __syncthreads();

    // ---- Phase B: qkv GEMM; A-frags streamed from LDS, B-frags from ws ----
    {
        const unsigned short* qw = ws + WS_QKVW;
        const int h2 = wv >> 1;                 // head this wave produces
        const int dhalf = wv & 1;
        const int dh = dhalf * 16 + l15;        // d within head 0..31
        #pragma unroll
        for (int pp = 0; pp < 3; pp++) {        // 0=q 1=k 2=v
            const int j = (pp * 8 + wv) * 16 + l15;
            bf16x8 bfr[4];
            #pragma unroll
            for (int ks_ = 0; ks_ < 4; ks_++)
                bfr[ks_] = *(const bf16x8*)(qw + j * DIMC + ks_ * 32 + qg * 8);
            const float bias = (pp == 0) ? qkv_b[j] * (SCALE * LOG2E) : qkv_b[j];
            #pragma unroll
            for (int mt = 0; mt < 4; mt++) {
                int ar = mt * 16 + l15; if (ar > 48) ar = 48;
                f32x4 acc = { bias, bias, bias, bias };
                #pragma unroll
                for (int ks_ = 0; ks_ < 4; ks_++) {
                    bf16x8 afm = *(const bf16x8*)(smem + XP_OFF + SWZ(ar, ks_ * 32 + qg * 8));
                    acc = __builtin_amdgcn_mfma_f32_16x16x32_bf16(afm, bfr[ks_], acc, 0, 0, 0);
                }
                if (pp == 0) {
                    #pragma unroll
                    for (int r = 0; r < 4; r++) {
                        int row = mt * 16 + qg * 4 + r;
                        if (row < NTOK)
                            smem[Q_OFF + SWZ(row, h2 * 32 + dh)] = f2b_r(acc[r]);
                    }
                } else if (pp == 1) {
                    #pragma unroll
                    for (int r = 0; r < 4; r++) {
                        int row = mt * 16 + qg * 4 + r;
                        if (row < NTOK)
                            smem[K_OFF + SWZ(row, h2 * 32 + dh)] = f2b_r(acc[r]);
                    }
                } else {
                    // V -> B-frag layout (verified mapping from R7)
                    int ks2 = mt >> 1;
                    int qgp = (mt & 1) * 2 + (qg >> 1);
                    int j0  = (qg & 1) * 4;
                    uint2 u; u.x = pkbf2(acc[0], acc[1]); u.y = pkbf2(acc[2], acc[3]);
                    *(uint2*)(smem + VB_OFF + h2 * 2048 + ks2 * 1024 + dhalf * 512
                              + qgp * 128 + l15 * 8 + j0) = u;
                }
            }
        }
    }
    __syncthreads();

    // ---- Phase C: attention; wave = (M-strip, head-pair) ----
    // x in XP is dead now: P overlays it. O overlays Q cols (own rows/heads).
    const int g  = wv >> 2;        // head group: heads {2g, 2g+1}
    const int st = wv & 3;         // M-strip
    const int r0 = st * 16;
    const int wy = w >> 3, wx = w & 7;
    int grow[4];
    #pragma unroll
    for (int r = 0; r < 4; r++) {
        int t = r0 + qg * 4 + r;
        int ty = (t * 9363) >> 16, tx = t - ty * 7;
        grow[r] = seg3(wy * 7 + ty) * 3 + seg3(wx * 7 + tx);
    }
    int arq = r0 + l15; if (arq > 48) arq = 48;

    #pragma unroll
    for (int hh = 0; hh < 2; hh++) {
        const int h = 2 * g + hh;
        // aq read BEFORE any O write lands in this column range (in-wave order:
        // hh=0 O-write hits cols 64g..+31; this hh=1 read is cols 64g+32..+63)
        const bf16x8 aq = *(const bf16x8*)(smem + Q_OFF + SWZ(arq, h * 32 + qg * 8));
        float sv[4][4];
        #pragma unroll
        for (int nt = 0; nt < 4; nt++) {
            int krow = nt * 16 + l15; if (krow > 48) krow = 48;
            bf16x8 bk = *(const bf16x8*)(smem + K_OFF + SWZ(krow, h * 32 + qg * 8));
            f32x4 z = { 0.f, 0.f, 0.f, 0.f };
            f32x4 c = __builtin_amdgcn_mfma_f32_16x16x32_bf16(aq, bk, z, 0, 0, 0);
            uint2 bb = *(const uint2*)(ws + WS_BIAS + (((h * 4 + st) * 4 + nt) * 64 + lane) * 4);
            int t = nt * 16 + l15;
            int ty = (t * 9363) >> 16, tx = t - ty * 7;
            int gcol = seg3(wy * 7 + ty) * 3 + seg3(wx * 7 + tx);
            bool vc = t < NTOK;
            float bv[4] = { b2f_lo(bb.x), b2f_hi(bb.x), b2f_lo(bb.y), b2f_hi(bb.y) };
            #pragma unroll
            for (int r = 0; r < 4; r++) {
                float v = c[r] + bv[r] + ((grow[r] == gcol) ? 0.f : NMASK);
                sv[nt][r] = vc ? v : -1e30f;
            }
        }
        float inv[4];
        #pragma unroll
        for (int r = 0; r < 4; r++) {
            float mx = fmaxf(fmaxf(sv[0][r], sv[1][r]), fmaxf(sv[2][r], sv[3][r]));
            mx = fmaxf(mx, __shfl_xor(mx, 1));
            mx = fmaxf(mx, __shfl_xor(mx, 2));
            mx = fmaxf(mx, __shfl_xor(mx, 4));
            mx = fmaxf(mx, __shfl_xor(mx, 8));
            float sum = 0.f;
            #pragma unroll
            for (int nt = 0; nt < 4; nt++) {
                float e = exp2_hw(sv[nt][r] - mx);   // logits pre-scaled by LOG2E
                sv[nt][r] = e; sum += e;
            }
            sum += __shfl_xor(sum, 1);
            sum += __shfl_xor(sum, 2);
            sum += __shfl_xor(sum, 4);
            sum += __shfl_xor(sum, 8);
            inv[r] = __builtin_amdgcn_rcpf(sum);     // deferred normalization
        }
        // P -> XP cols g*64.. (own strip rows; x dead; cross-wave rows disjoint)
        #pragma unroll
        for (int nt = 0; nt < 4; nt++)
            #pragma unroll
            for (int r = 0; r < 4; r++) {
                int row = r0 + qg * 4 + r;
                if (row < NTOK)
                    smem[XP_OFF + SWZ(row, g * 64 + nt * 16 + l15)] = f2b_r(sv[nt][r]);
            }
        // PV: A = P strip (XP), B = V frags (linear, conflict-free)
        f32x4 accO[2] = { { 0.f, 0.f, 0.f, 0.f }, { 0.f, 0.f, 0.f, 0.f } };
        #pragma unroll
        for (int ks2 = 0; ks2 < 2; ks2++) {
            bf16x8 ap = *(const bf16x8*)(smem + XP_OFF + SWZ(arq, g * 64 + ks2 * 32 + qg * 8));
            #pragma unroll
            for (int nt2 = 0; nt2 < 2; nt2++) {
                bf16x8 bvv = *(const bf16x8*)(smem + VB_OFF + h * 2048 + ks2 * 1024 + nt2 * 512 + lane * 8);
                accO[nt2] = __builtin_amdgcn_mfma_f32_16x16x32_bf16(ap, bvv, accO[nt2], 0, 0, 0);
            }
        }
        // O -> Q cols h*32.. immediately (clobbers only own-wave's pre-read aq)
        #pragma unroll
        for (int nt2 = 0; nt2 < 2; nt2++)
            #pragma unroll
            for (int r = 0; r < 4; r++) {
                int row = r0 + qg * 4 + r;
                if (row < NTOK)
                    smem[Q_OFF + SWZ(row, h * 32 + nt2 * 16 + l15)] =
                        f2b_r(accO[nt2][r] * inv[r]);
            }
    }
    __syncthreads();

    // ---- Phase D: proj; wave = (M-strip, col-half) ----
    {
        const int mt = wv & 3, jh = wv >> 2;
        int ar = mt * 16 + l15; if (ar > 48) ar = 48;
        bf16x8 ad[4];
        #pragma unroll
        for (int ks_ = 0; ks_ < 4; ks_++)   // k-block = head block of attn-out
            ad[ks_] = *(const bf16x8*)(smem + Q_OFF + SWZ(ar, ks_ * 32 + qg * 8));
        const unsigned short* pw = ws + WS_PROJW;
        float* ob = out + (size_t)b * (NTOK * DIMC);
        #pragma unroll
        for (int jt2 = 0; jt2 < 4; jt2++) {
            const int j = jh * 64 + jt2 * 16 + l15;
            bf16x8 bfr[4];
            #pragma unroll
            for (int ks_ = 0; ks_ < 4; ks_++)
                bfr[ks_] = *(const bf16x8*)(pw + j * DIMC + ks_ * 32 + qg * 8);
            const float pb = proj_b[j];
            f32x4 acc = { pb, pb, pb, pb };
            #pragma unroll
            for (int ks_ = 0; ks_ < 4; ks_++)
                acc = __builtin_amdgcn_mfma_f32_16x16x32_bf16(ad[ks_], bfr[ks_], acc, 0, 0, 0);
            #pragma unroll
            for (int r = 0; r < 4; r++) {
                int row = mt * 16 + qg * 4 + r;
                if (row < NTOK) ob[row * DIMC + j] = acc[r];
            }
        }
    }
}

extern "C" void kernel_launch(void* const* d_in, const int* in_sizes, int n_in,
                              void* d_out, int out_size, void* d_ws, size_t ws_size,
                              hipStream_t stream) {
    const float* x      = (const float*)d_in[0];
    // d_in[1] = mask (recomputed arithmetically)
    const float* qkv_w  = (const float*)d_in[2];
    const float* qkv_b  = (const float*)d_in[3];
    const float* proj_w = (const float*)d_in[4];
    const float* proj_b = (const float*)d_in[5];
    const float* bias_t = (const float*)d_in[6];
    const int*   relidx = (const int*)d_in[7];
    float*       outp   = (float*)d_out;
    unsigned short* ws  = (unsigned short*)d_ws;

    prep<<<96, 256, 0, stream>>>(qkv_w, proj_w, bias_t, relidx, ws);
    win_attn<<<NBLK, 512, 0, stream>>>(x, qkv_b, proj_b, ws, outp);
}

// Round 4
// 298.243 us; speedup vs baseline: 1.4349x; 1.4349x over previous
//
#include <hip/hip_runtime.h>

// Swin window attention, MFMA bf16 path. fp32 global in/out.
// R9: R8 layout (LDS 54,016B -> 3 blocks/CU by LDS alone) with the spill bug
// fixed: __launch_bounds__(512,4) (cap 128). R7/R8's (512,6) capped VGPR at
// ~85 and the allocator spilled ~600MB/dispatch of scratch (FETCH 277MB /
// WRITE 471MB vs ~150MB real traffic). R6 proved (512,4) => VGPR 56, no
// spill; at VGPR<=80 the HW grants 24 waves/CU (3 blocks) from LDS+VGPR
// naturally. Layout: x in XP (P overlays in C), Q/O share, K separate,
// V dense B-frags; stride-128 + XOR swizzle. Barriers: 3.

#define NTOK  49
#define DIMC  128
#define NBLK  4096
#define SCALE 0.17677669529663687f   // 32^-0.5
#define LOG2E 1.4426950408889634f
#define NMASK -144.26950408889634f   // -100 * LOG2E

typedef __attribute__((ext_vector_type(8))) short bf16x8;
typedef __attribute__((ext_vector_type(4))) float f32x4;

// ---- workspace layout (ushort units) ----
#define WS_QKVW 0        // 384*128 bf16 (q rows pre-scaled by SCALE*LOG2E)
#define WS_PROJW 49152   // 128*128 bf16
#define WS_BIAS  65536   // [h][mt][nt][lane][reg] 4*4*4*64*4 bf16 (x LOG2E)

// ---- LDS layout (ushort units) ----
// XP: [49][128] swz: x stage (Phase A/B) -> P [2 g][49][64 keys] (Phase C).
// Q : [49][128] swz: Q (col=h*32+d); attn-out O overlays same cols in C.
// K : [49][128] swz.
// VB: V as B-frags [4 h][2 ks2][2 nt2][64 lane][8] (linear, conflict-free).
#define XP_OFF 0
#define Q_OFF  6272
#define K_OFF  12544
#define VB_OFF 18816
#define SMEM_TOT 27008   // 54,016 B -> 3 blocks/CU @ 512 thr = 24 waves/CU

// XOR swizzle: row-major [49][128] shorts, granule 8 shorts (16B).
#define SWZ(r, c) ((r) * 128 + ((c) ^ (((r) & 7) << 3)))

__device__ __forceinline__ unsigned int pkbf2(float f0, float f1) {
    union { float f; unsigned int i; } a, b; a.f = f0; b.f = f1;
    return __builtin_amdgcn_perm(b.i + 0x8000u, a.i + 0x8000u, 0x07060302u);
}
__device__ __forceinline__ unsigned short f2b_r(float f) {
    union { float f; unsigned int i; } v; v.f = f;
    return (unsigned short)((v.i + 0x8000u) >> 16);
}
__device__ __forceinline__ float b2f_lo(unsigned int u) {
    union { unsigned int i; float f; } v; v.i = u << 16; return v.f;
}
__device__ __forceinline__ float b2f_hi(unsigned int u) {
    union { unsigned int i; float f; } v; v.i = u & 0xFFFF0000u; return v.f;
}
__device__ __forceinline__ float exp2_hw(float x) {
    float r; asm("v_exp_f32 %0, %1" : "=v"(r) : "v"(x)); return r;
}

// Swin shift-mask group id. GRID=56, WS=7, shift=3: segments [0,49)/[49,53)/[53,56)
__device__ __forceinline__ int seg3(int c) { return (c < 49) ? 0 : ((c < 53) ? 1 : 2); }

// ---------------- prep: weights fp32->bf16 (+SCALE*LOG2E fold), bias -> frag order
__global__ __launch_bounds__(256)
void prep(const float* __restrict__ qkv_w, const float* __restrict__ proj_w,
          const float* __restrict__ bias_t, const int* __restrict__ rel_idx,
          unsigned short* __restrict__ ws)
{
    int idx = blockIdx.x * 256 + threadIdx.x;
    if (idx < 8192) {
        int base = idx * 8;
        const float* sp = (base < 49152) ? (qkv_w + base) : (proj_w + (base - 49152));
        float sc = (base < 16384) ? (SCALE * LOG2E) : 1.0f;  // q rows pre-scaled
        float4 a = *(const float4*)sp;
        float4 b = *(const float4*)(sp + 4);
        uint4 u;
        u.x = pkbf2(a.x * sc, a.y * sc);
        u.y = pkbf2(a.z * sc, a.w * sc);
        u.z = pkbf2(b.x * sc, b.y * sc);
        u.w = pkbf2(b.z * sc, b.w * sc);
        *(uint4*)(ws + base) = u;
    } else {
        int i = idx - 8192;                         // [0, 16384)
        int reg = i & 3, lane = (i >> 2) & 63, nt = (i >> 8) & 3,
            mt = (i >> 10) & 3, h = (i >> 12) & 3;
        int row = mt * 16 + (lane >> 4) * 4 + reg;
        int col = nt * 16 + (lane & 15);
        float v = 0.f;
        if (row < NTOK && col < NTOK)
            v = bias_t[rel_idx[row * NTOK + col] * 4 + h] * LOG2E;
        ws[WS_BIAS + i] = f2b_r(v);
    }
}

// ---------------- main: 512 threads = 8 waves, one window ----------------
__global__ __launch_bounds__(512, 4)
void win_attn(const float* __restrict__ x,
              const float* __restrict__ qkv_b,
              const float* __restrict__ proj_b,
              const unsigned short* __restrict__ ws,
              float* __restrict__ out)
{
    __shared__ unsigned short smem[SMEM_TOT];
    const int b    = blockIdx.x;
    const int w    = b & 63;
    const int tid  = threadIdx.x;
    const int wv   = tid >> 6;     // wave id 0..7
    const int lane = tid & 63;
    const int qg   = lane >> 4;    // quad
    const int l15  = lane & 15;

    // ---- Phase A: stage x -> bf16 LDS [49][128] swz in XP ----
    {
        const float4* xg = (const float4*)(x + (size_t)b * (NTOK * DIMC));
        #pragma unroll
        for (int it = 0; it < 4; it++) {
            int i = tid + it * 512;
            if (i < NTOK * DIMC / 4) {
                float4 v = xg[i];
                int row = i >> 5, col = (i & 31) * 4;
                uint2 u; u.x = pkbf2(v.x, v.y); u.y = pkbf2(v.z, v.w);
                *(uint2*)(smem + XP_OFF + SWZ(row, col)) = u;
            }
        }
    }
    __syncthreads();

    // ---- Phase B: qkv GEMM; A-frags streamed from LDS, B-frags from ws ----
    {
        const unsigned short* qw = ws + WS_QKVW;
        const int h2 = wv >> 1;                 // head this wave produces
        const int dhalf = wv & 1;
        const int dh = dhalf * 16 + l15;        // d within head 0..31
        #pragma unroll
        for (int pp = 0; pp < 3; pp++) {        // 0=q 1=k 2=v
            const int j = (pp * 8 + wv) * 16 + l15;
            bf16x8 bfr[4];
            #pragma unroll
            for (int ks_ = 0; ks_ < 4; ks_++)
                bfr[ks_] = *(const bf16x8*)(qw + j * DIMC + ks_ * 32 + qg * 8);
            const float bias = (pp == 0) ? qkv_b[j] * (SCALE * LOG2E) : qkv_b[j];
            #pragma unroll
            for (int mt = 0; mt < 4; mt++) {
                int ar = mt * 16 + l15; if (ar > 48) ar = 48;
                f32x4 acc = { bias, bias, bias, bias };
                #pragma unroll
                for (int ks_ = 0; ks_ < 4; ks_++) {
                    bf16x8 afm = *(const bf16x8*)(smem + XP_OFF + SWZ(ar, ks_ * 32 + qg * 8));
                    acc = __builtin_amdgcn_mfma_f32_16x16x32_bf16(afm, bfr[ks_], acc, 0, 0, 0);
                }
                if (pp == 0) {
                    #pragma unroll
                    for (int r = 0; r < 4; r++) {
                        int row = mt * 16 + qg * 4 + r;
                        if (row < NTOK)
                            smem[Q_OFF + SWZ(row, h2 * 32 + dh)] = f2b_r(acc[r]);
                    }
                } else if (pp == 1) {
                    #pragma unroll
                    for (int r = 0; r < 4; r++) {
                        int row = mt * 16 + qg * 4 + r;
                        if (row < NTOK)
                            smem[K_OFF + SWZ(row, h2 * 32 + dh)] = f2b_r(acc[r]);
                    }
                } else {
                    // V -> B-frag layout (verified mapping from R7)
                    int ks2 = mt >> 1;
                    int qgp = (mt & 1) * 2 + (qg >> 1);
                    int j0  = (qg & 1) * 4;
                    uint2 u; u.x = pkbf2(acc[0], acc[1]); u.y = pkbf2(acc[2], acc[3]);
                    *(uint2*)(smem + VB_OFF + h2 * 2048 + ks2 * 1024 + dhalf * 512
                              + qgp * 128 + l15 * 8 + j0) = u;
                }
            }
        }
    }
    __syncthreads();

    // ---- Phase C: attention; wave = (M-strip, head-pair) ----
    // x in XP is dead now: P overlays it. O overlays Q cols (own rows/heads).
    const int g  = wv >> 2;        // head group: heads {2g, 2g+1}
    const int st = wv & 3;         // M-strip
    const int r0 = st * 16;
    const int wy = w >> 3, wx = w & 7;
    int grow[4];
    #pragma unroll
    for (int r = 0; r < 4; r++) {
        int t = r0 + qg * 4 + r;
        int ty = (t * 9363) >> 16, tx = t - ty * 7;
        grow[r] = seg3(wy * 7 + ty) * 3 + seg3(wx * 7 + tx);
    }
    int arq = r0 + l15; if (arq > 48) arq = 48;

    #pragma unroll
    for (int hh = 0; hh < 2; hh++) {
        const int h = 2 * g + hh;
        // aq read BEFORE any O write lands in this column range (in-wave order:
        // hh=0 O-write hits cols 64g..+31; this hh=1 read is cols 64g+32..+63)
        const bf16x8 aq = *(const bf16x8*)(smem + Q_OFF + SWZ(arq, h * 32 + qg * 8));
        float sv[4][4];
        #pragma unroll
        for (int nt = 0; nt < 4; nt++) {
            int krow = nt * 16 + l15; if (krow > 48) krow = 48;
            bf16x8 bk = *(const bf16x8*)(smem + K_OFF + SWZ(krow, h * 32 + qg * 8));
            f32x4 z = { 0.f, 0.f, 0.f, 0.f };
            f32x4 c = __builtin_amdgcn_mfma_f32_16x16x32_bf16(aq, bk, z, 0, 0, 0);
            uint2 bb = *(const uint2*)(ws + WS_BIAS + (((h * 4 + st) * 4 + nt) * 64 + lane) * 4);
            int t = nt * 16 + l15;
            int ty = (t * 9363) >> 16, tx = t - ty * 7;
            int gcol = seg3(wy * 7 + ty) * 3 + seg3(wx * 7 + tx);
            bool vc = t < NTOK;
            float bv[4] = { b2f_lo(bb.x), b2f_hi(bb.x), b2f_lo(bb.y), b2f_hi(bb.y) };
            #pragma unroll
            for (int r = 0; r < 4; r++) {
                float v = c[r] + bv[r] + ((grow[r] == gcol) ? 0.f : NMASK);
                sv[nt][r] = vc ? v : -1e30f;
            }
        }
        float inv[4];
        #pragma unroll
        for (int r = 0; r < 4; r++) {
            float mx = fmaxf(fmaxf(sv[0][r], sv[1][r]), fmaxf(sv[2][r], sv[3][r]));
            mx = fmaxf(mx, __shfl_xor(mx, 1));
            mx = fmaxf(mx, __shfl_xor(mx, 2));
            mx = fmaxf(mx, __shfl_xor(mx, 4));
            mx = fmaxf(mx, __shfl_xor(mx, 8));
            float sum = 0.f;
            #pragma unroll
            for (int nt = 0; nt < 4; nt++) {
                float e = exp2_hw(sv[nt][r] - mx);   // logits pre-scaled by LOG2E
                sv[nt][r] = e; sum += e;
            }
            sum += __shfl_xor(sum, 1);
            sum += __shfl_xor(sum, 2);
            sum += __shfl_xor(sum, 4);
            sum += __shfl_xor(sum, 8);
            inv[r] = __builtin_amdgcn_rcpf(sum);     // deferred normalization
        }
        // P -> XP cols g*64.. (own strip rows; x dead; cross-wave rows disjoint)
        #pragma unroll
        for (int nt = 0; nt < 4; nt++)
            #pragma unroll
            for (int r = 0; r < 4; r++) {
                int row = r0 + qg * 4 + r;
                if (row < NTOK)
                    smem[XP_OFF + SWZ(row, g * 64 + nt * 16 + l15)] = f2b_r(sv[nt][r]);
            }
        // PV: A = P strip (XP), B = V frags (linear, conflict-free)
        f32x4 accO[2] = { { 0.f, 0.f, 0.f, 0.f }, { 0.f, 0.f, 0.f, 0.f } };
        #pragma unroll
        for (int ks2 = 0; ks2 < 2; ks2++) {
            bf16x8 ap = *(const bf16x8*)(smem + XP_OFF + SWZ(arq, g * 64 + ks2 * 32 + qg * 8));
            #pragma unroll
            for (int nt2 = 0; nt2 < 2; nt2++) {
                bf16x8 bvv = *(const bf16x8*)(smem + VB_OFF + h * 2048 + ks2 * 1024 + nt2 * 512 + lane * 8);
                accO[nt2] = __builtin_amdgcn_mfma_f32_16x16x32_bf16(ap, bvv, accO[nt2], 0, 0, 0);
            }
        }
        // O -> Q cols h*32.. immediately (clobbers only own-wave's pre-read aq)
        #pragma unroll
        for (int nt2 = 0; nt2 < 2; nt2++)
            #pragma unroll
            for (int r = 0; r < 4; r++) {
                int row = r0 + qg * 4 + r;
                if (row < NTOK)
                    smem[Q_OFF + SWZ(row, h * 32 + nt2 * 16 + l15)] =
                        f2b_r(accO[nt2][r] * inv[r]);
            }
    }
    __syncthreads();

    // ---- Phase D: proj; wave = (M-strip, col-half) ----
    {
        const int mt = wv & 3, jh = wv >> 2;
        int ar = mt * 16 + l15; if (ar > 48) ar = 48;
        bf16x8 ad[4];
        #pragma unroll
        for (int ks_ = 0; ks_ < 4; ks_++)   // k-block = head block of attn-out
            ad[ks_] = *(const bf16x8*)(smem + Q_OFF + SWZ(ar, ks_ * 32 + qg * 8));
        const unsigned short* pw = ws + WS_PROJW;
        float* ob = out + (size_t)b * (NTOK * DIMC);
        #pragma unroll
        for (int jt2 = 0; jt2 < 4; jt2++) {
            const int j = jh * 64 + jt2 * 16 + l15;
            bf16x8 bfr[4];
            #pragma unroll
            for (int ks_ = 0; ks_ < 4; ks_++)
                bfr[ks_] = *(const bf16x8*)(pw + j * DIMC + ks_ * 32 + qg * 8);
            const float pb = proj_b[j];
            f32x4 acc = { pb, pb, pb, pb };
            #pragma unroll
            for (int ks_ = 0; ks_ < 4; ks_++)
                acc = __builtin_amdgcn_mfma_f32_16x16x32_bf16(ad[ks_], bfr[ks_], acc, 0, 0, 0);
            #pragma unroll
            for (int r = 0; r < 4; r++) {
                int row = mt * 16 + qg * 4 + r;
                if (row < NTOK) ob[row * DIMC + j] = acc[r];
            }
        }
    }
}

extern "C" void kernel_launch(void* const* d_in, const int* in_sizes, int n_in,
                              void* d_out, int out_size, void* d_ws, size_t ws_size,
                              hipStream_t stream) {
    const float* x      = (const float*)d_in[0];
    // d_in[1] = mask (recomputed arithmetically)
    const float* qkv_w  = (const float*)d_in[2];
    const float* qkv_b  = (const float*)d_in[3];
    const float* proj_w = (const float*)d_in[4];
    const float* proj_b = (const float*)d_in[5];
    const float* bias_t = (const float*)d_in[6];
    const int*   relidx = (const int*)d_in[7];
    float*       outp   = (float*)d_out;
    unsigned short* ws  = (unsigned short*)d_ws;

    prep<<<96, 256, 0, stream>>>(qkv_w, proj_w, bias_t, relidx, ws);
    win_attn<<<NBLK, 512, 0, stream>>>(x, qkv_b, proj_b, ws, outp);
}